// Round 11
// baseline (161.659 us; speedup 1.0000x reference)
//
#include <hip/hip_runtime.h>

// y = q_tok(x) @ q_grp(W)^T + bias, factored exactly:
//   q(x) = g_x * s_x[m], q(W) = g_w * s_w[n,grp] (grp=128 along K)
//   y[m,n] = s_x[m] * sum_grp s_w[n,grp] * (sum_{k in grp} g_x g_w)
// R16: gemm ported to the 8-phase-family schedule (m233/m218: counted
// vmcnt with loads SPANNING phases is the lever; per-period drain was the
// residual stall). BM=128 x BN=256, 512 thr / 8 waves (2m x 4n, wave tile
// 64x64), grid 256 = 1 block/CU tail-free. 3-slot LDS, prefetch distance
// 2, static slots (unroll-by-3). Per group: {issue As(g+2); vmcnt(4); B1;
// 8 ds reads | issue Bs(g+2) | 4 ds reads; lgkm(4); 8 MFMA; lgkm(0);
// 8 MFMA; B_end}. Slot release: stage into (g+2)%3==(g-1)%3 issues after
// g-1's end barrier (all reads retired via per-wave lgkm(0)). Swizzle +
// setprio kept. Quant unchanged (R15).

#define M_TOK 2048
#define N_OUT 4096
#define K_IN  4096
#define KB    2048    // packed fp4 bytes per K row (K_IN/2)
#define XBLK  2048    // x-role: one block per token row
#define WBLK  8192    // w-role: 2048 floats (16 groups) per block

typedef __attribute__((ext_vector_type(4))) int   int4v;
typedef __attribute__((ext_vector_type(8))) int   int8v;
typedef __attribute__((ext_vector_type(4))) float floatx4;

// fp4-e2m1 nibble via scale-premultiplied decision thresholds
// T = {.25,.75,1.25,1.75,2.5,3.5,5}*scale; codes 0..7 = {0,.5,1,1.5,2,3,4,6}
__device__ __forceinline__ unsigned int q_nib(
    float v, float t0, float t1, float t2, float t3, float t4, float t5, float t6)
{
    float a = fabsf(v);
    unsigned int m =
        a < t0 ? 0u : a < t1 ? 1u : a < t2 ? 2u : a < t3 ? 3u :
        a < t4 ? 4u : a < t5 ? 5u : a < t6 ? 6u : 7u;
    return m | ((__float_as_uint(v) >> 28) & 0x8u);
}

#define MK_THR(scale) \
    const float t0 = 0.25f * (scale), t1 = 0.75f * (scale), \
                t2 = 1.25f * (scale), t3 = 1.75f * (scale), \
                t4 = 2.5f  * (scale), t5 = 3.5f  * (scale), \
                t6 = 5.0f  * (scale);

// ---------- fused quant: blocks [0,XBLK) per-token x, rest per-group w ----------
__global__ __launch_bounds__(256) void quant_fused_kernel(
    const float* __restrict__ x, const float* __restrict__ w,
    unsigned char* __restrict__ xq, float* __restrict__ sx,
    unsigned char* __restrict__ wq, float* __restrict__ swt)
{
    const int t = threadIdx.x;
    const int lane = t & 63, wid = t >> 6;

    if (blockIdx.x < XBLK) {
        // ---- per-token row of 4096: clamp [-3,3], scale = absmax/6 ----
        const int row = blockIdx.x;
        const float* xr = x + (size_t)row * K_IN;
        float4 v[4];
        float amax = 0.0f;
        #pragma unroll
        for (int i = 0; i < 4; i++) {
            float4 a = *(const float4*)(xr + i * 1024 + t * 4);
            a.x = fminf(fmaxf(a.x, -3.0f), 3.0f);
            a.y = fminf(fmaxf(a.y, -3.0f), 3.0f);
            a.z = fminf(fmaxf(a.z, -3.0f), 3.0f);
            a.w = fminf(fmaxf(a.w, -3.0f), 3.0f);
            v[i] = a;
            amax = fmaxf(amax, fmaxf(fmaxf(fabsf(a.x), fabsf(a.y)),
                                     fmaxf(fabsf(a.z), fabsf(a.w))));
        }
        #pragma unroll
        for (int off = 32; off; off >>= 1)
            amax = fmaxf(amax, __shfl_xor(amax, off));
        __shared__ float smax[4];
        if (lane == 0) smax[wid] = amax;
        __syncthreads();
        amax = fmaxf(fmaxf(smax[0], smax[1]), fmaxf(smax[2], smax[3]));

        const float scale = amax / 6.0f;
        if (t == 0) sx[row] = scale;
        MK_THR(scale);
        unsigned char* xo = xq + (size_t)row * KB;
        #pragma unroll
        for (int i = 0; i < 4; i++) {
            unsigned int u = q_nib(v[i].x, t0,t1,t2,t3,t4,t5,t6)
                           | (q_nib(v[i].y, t0,t1,t2,t3,t4,t5,t6) << 4)
                           | (q_nib(v[i].z, t0,t1,t2,t3,t4,t5,t6) << 8)
                           | (q_nib(v[i].w, t0,t1,t2,t3,t4,t5,t6) << 12);
            *(unsigned short*)(xo + i * 512 + t * 2) = (unsigned short)u;
        }
    } else {
        // ---- per-group w: block = 2048 floats = 16 groups. Phase p,
        // thread t owns floats [p*1024 + t*4, +4) (16B/lane contiguous),
        // all inside group p*8 + (t>>5). 32-lane cluster reduce. ----
        const int b = blockIdx.x - XBLK;
        const float* base = w + (size_t)b * 2048;
        float4 va = *(const float4*)(base + t * 4);
        float4 vb = *(const float4*)(base + 1024 + t * 4);
        #pragma unroll
        for (int p = 0; p < 2; p++) {
            float4 a = p ? vb : va;
            float amax = fmaxf(fmaxf(fabsf(a.x), fabsf(a.y)),
                               fmaxf(fabsf(a.z), fabsf(a.w)));
            #pragma unroll
            for (int off = 16; off; off >>= 1)   // reduce 32-lane cluster
                amax = fmaxf(amax, __shfl_xor(amax, off));
            const float scale = amax / 6.0f;
            const int G = b * 16 + p * 8 + (t >> 5);  // flat group = n*32+gk
            if ((t & 31) == 0)
                swt[(size_t)(G & 31) * N_OUT + (G >> 5)] = scale;
            MK_THR(scale);
            unsigned int u = q_nib(a.x, t0,t1,t2,t3,t4,t5,t6)
                           | (q_nib(a.y, t0,t1,t2,t3,t4,t5,t6) << 4)
                           | (q_nib(a.z, t0,t1,t2,t3,t4,t5,t6) << 8)
                           | (q_nib(a.w, t0,t1,t2,t3,t4,t5,t6) << 12);
            *(unsigned short*)(wq + (size_t)b * 1024 + p * 512 + t * 2) =
                (unsigned short)u;
        }
    }
}

// ---------- async 16B global->LDS ----------
__device__ __forceinline__ void gld16(const unsigned char* g, unsigned char* l) {
    __builtin_amdgcn_global_load_lds(
        (const __attribute__((address_space(1))) void*)g,
        (__attribute__((address_space(3))) void*)l, 16, 0, 0);
}

// fragment read with the 8-row-period swizzle (verified 0-conflict, R9/R11)
__device__ __forceinline__ int4v frag4(const unsigned char* buf, int row, int lq) {
    const int slot = (lq + (row >> 1)) & 3;
    return *(const int4v*)&buf[row * 64 + slot * 16];
}
__device__ __forceinline__ int8v ext8(int4v d) {
    return (int8v){d[0], d[1], d[2], d[3], 0, 0, 0, 0};
}

// ---------- MX-fp4 GEMM, BK=128, 8-phase-family schedule ----------
// BM=128, BN=256, 8 waves (2m x 4n), wave tile 64x64. 3-slot LDS,
// prefetch distance 2, counted vmcnt (never drains in steady state),
// two lgkm-counted MFMA phases per group, setprio, 2 barriers/group.
__global__ __launch_bounds__(512, 2) void gemm_mx4_kernel(
    const unsigned char* __restrict__ A, const float* __restrict__ sx,
    const unsigned char* __restrict__ B, const float* __restrict__ swt,
    const float* __restrict__ bias, float* __restrict__ C)
{
    __shared__ __align__(16) unsigned char As[3][128 * 64];  // 24 KB
    __shared__ __align__(16) unsigned char Bs[3][256 * 64];  // 48 KB
    __shared__ __align__(16) float svs[32][256];             // 32 KB

    const int tid = threadIdx.x;             // 0..511
    const int m0 = blockIdx.y * 128;
    const int n0 = blockIdx.x * 256;
    const int lane = tid & 63;
    const int wid  = tid >> 6;               // 0..7
    const int wm = (wid & 1) * 64;           // m-wave: 0/64
    const int wn = (wid >> 1) * 64;          // n-wave: 0/64/128/192
    const int lr = lane & 15;
    const int lq = lane >> 4;

    floatx4 mast[4][4] = {};

    // staging addresses, swizzle phys-slot = (c + (row>>1)) & 3 (inverse on
    // the global source; LDS dest stays wave-uniform + lane*16).
    // As: 512 chunks -> 1/thread. Bs: 1024 chunks -> 2/thread.
    const unsigned char* gA;
    int ldstA;
    {
        const int P = tid;
        const int row = P >> 2, ph = P & 3;
        const int c = (ph - (row >> 1)) & 3;
        gA = A + (size_t)(m0 + row) * KB + c * 16;
        ldstA = P * 16;
    }
    const unsigned char* gB[2];
    int ldstB[2];
    #pragma unroll
    for (int j = 0; j < 2; j++) {
        const int P = tid + j * 512;
        const int row = P >> 2, ph = P & 3;
        const int c = (ph - (row >> 1)) & 3;
        gB[j] = B + (size_t)(n0 + row) * KB + c * 16;
        ldstB[j] = P * 16;
    }

#define STAGE_AS(gg, ss) gld16(gA + (gg) * 64, &As[ss][ldstA])
#define STAGE_BS(gg, ss) do {                                  \
        gld16(gB[0] + (gg) * 64, &Bs[ss][ldstB[0]]);           \
        gld16(gB[1] + (gg) * 64, &Bs[ss][ldstB[1]]);           \
    } while (0)

    // one-time stage of this block's weight scales: swt[g][n0..n0+256)
    // (global loads + ds_writes BEFORE any gld16 so their implicit waits
    // don't drain the staging queue)
    {
        float4 tmp[4];
        #pragma unroll
        for (int i = 0; i < 4; i++) {
            const int flat = tid + i * 512;      // float4 index, 2048 total
            const int g = flat >> 6, c = (flat & 63) << 2;
            tmp[i] = *(const float4*)(swt + (size_t)g * N_OUT + n0 + c);
        }
        #pragma unroll
        for (int i = 0; i < 4; i++) {
            const int flat = tid + i * 512;
            const int g = flat >> 6, c = (flat & 63) << 2;
            *(float4*)&svs[g][c] = tmp[i];
        }
    }
    // prologue: tiles 0,1 into slots 0,1 (6 gld16 in flight)
    STAGE_AS(0, 0); STAGE_BS(0, 0);
    STAGE_AS(1, 1); STAGE_BS(1, 1);
    asm volatile("s_waitcnt lgkmcnt(0)" ::: "memory");  // svs ds_writes done

    const floatx4 zero = {0.0f, 0.0f, 0.0f, 0.0f};

    // Per group G (slot SC=G%3, stage slot SS=(G+2)%3):
    //   STAGE_AS(G+2,SS) ; vmcnt(N) ; B1 (publish SC; SS-overwrite safe:
    //   previous group's end barrier certified all reads retired) ;
    //   reads A-phase (2 sv + 4 a + 2 b = 8 ds) ; STAGE_BS(G+2,SS) ;
    //   reads B-phase (2 sv + 2 b = 4 ds) ; lgkm(4) -> 8 MFMA ;
    //   lgkm(0) -> 8 MFMA ; B_end.
    // vmcnt ledger: at vmcnt point outstanding <= 7 (tile G 3, tile G+1 3,
    // new As 1); vmcnt(4) retires exactly tile G. Tails: G=30 -> 3, 31 -> 0.
#define BODY(G, SC, SS, STG, VMSTR) do {                                     \
        if (STG) STAGE_AS((G) + 2, SS);                                      \
        asm volatile("s_waitcnt " VMSTR ::: "memory");                       \
        __builtin_amdgcn_s_barrier();            /* B1: slot SC published */ \
        __builtin_amdgcn_sched_barrier(0);                                   \
        float sv0_ = svs[G][wn + lr];                                        \
        float sv1_ = svs[G][wn + 16 + lr];                                   \
        int4v a_[4], b_[4];                                                  \
        _Pragma("unroll")                                                    \
        for (int mi = 0; mi < 4; mi++)                                       \
            a_[mi] = frag4(As[SC], wm + mi * 16 + lr, lq);                   \
        b_[0] = frag4(Bs[SC], wn + lr, lq);                                  \
        b_[1] = frag4(Bs[SC], wn + 16 + lr, lq);                             \
        __builtin_amdgcn_sched_barrier(0);       /* pin A-phase reads */     \
        if (STG) STAGE_BS((G) + 2, SS);                                      \
        float sv2_ = svs[G][wn + 32 + lr];                                   \
        float sv3_ = svs[G][wn + 48 + lr];                                   \
        b_[2] = frag4(Bs[SC], wn + 32 + lr, lq);                             \
        b_[3] = frag4(Bs[SC], wn + 48 + lr, lq);                             \
        asm volatile("s_waitcnt lgkmcnt(4)" ::: "memory");                   \
        __builtin_amdgcn_sched_barrier(0);       /* rule #18 */              \
        __builtin_amdgcn_s_setprio(1);                                       \
        _Pragma("unroll")                                                    \
        for (int mi = 0; mi < 4; mi++) {                                     \
            floatx4 t0_ = __builtin_amdgcn_mfma_scale_f32_16x16x128_f8f6f4(  \
                ext8(a_[mi]), ext8(b_[0]), zero, 4, 4,                       \
                0, 0x7F7F7F7F, 0, 0x7F7F7F7F);                               \
            mast[mi][0] += sv0_ * t0_;                                       \
            floatx4 t1_ = __builtin_amdgcn_mfma_scale_f32_16x16x128_f8f6f4(  \
                ext8(a_[mi]), ext8(b_[1]), zero, 4, 4,                       \
                0, 0x7F7F7F7F, 0, 0x7F7F7F7F);                               \
            mast[mi][1] += sv1_ * t1_;                                       \
        }                                                                    \
        __builtin_amdgcn_s_setprio(0);                                       \
        asm volatile("s_waitcnt lgkmcnt(0)" ::: "memory");                   \
        __builtin_amdgcn_sched_barrier(0);       /* rule #18 */              \
        __builtin_amdgcn_s_setprio(1);                                       \
        _Pragma("unroll")                                                    \
        for (int mi = 0; mi < 4; mi++) {                                     \
            floatx4 t2_ = __builtin_amdgcn_mfma_scale_f32_16x16x128_f8f6f4(  \
                ext8(a_[mi]), ext8(b_[2]), zero, 4, 4,                       \
                0, 0x7F7F7F7F, 0, 0x7F7F7F7F);                               \
            mast[mi][2] += sv2_ * t2_;                                       \
            floatx4 t3_ = __builtin_amdgcn_mfma_scale_f32_16x16x128_f8f6f4(  \
                ext8(a_[mi]), ext8(b_[3]), zero, 4, 4,                       \
                0, 0x7F7F7F7F, 0, 0x7F7F7F7F);                               \
            mast[mi][3] += sv3_ * t3_;                                       \
        }                                                                    \
        __builtin_amdgcn_s_setprio(0);                                       \
        __builtin_amdgcn_s_barrier();            /* B_end: reads retired */  \
    } while (0)

    #pragma unroll 1
    for (int g = 0; g < 30; g += 3) {
        BODY(g + 0, 0, 2, 1, "vmcnt(4)");
        BODY(g + 1, 1, 0, 1, "vmcnt(4)");
        BODY(g + 2, 2, 1, 1, "vmcnt(4)");
    }
    BODY(30, 0, 2, 0, "vmcnt(3)");
    BODY(31, 1, 2, 0, "vmcnt(0)");
#undef BODY
#undef STAGE_AS
#undef STAGE_BS

    // epilogue: C/D layout col=lane&15, row=(lane>>4)*4+reg [m89/m91]
    #pragma unroll
    for (int mi = 0; mi < 4; mi++) {
        const int rbase = m0 + wm + mi * 16 + lq * 4;
        #pragma unroll
        for (int ni = 0; ni < 4; ni++) {
            const int cc = n0 + wn + ni * 16 + lr;
            const float bb = bias[cc];
            #pragma unroll
            for (int r = 0; r < 4; r++)
                C[(size_t)(rbase + r) * N_OUT + cc] =
                    sx[rbase + r] * mast[mi][ni][r] + bb;
        }
    }
}

extern "C" void kernel_launch(void* const* d_in, const int* in_sizes, int n_in,
                              void* d_out, int out_size, void* d_ws, size_t ws_size,
                              hipStream_t stream) {
    const float* x    = (const float*)d_in[0];
    const float* w    = (const float*)d_in[1];
    const float* bias = (const float*)d_in[2];
    float* out = (float*)d_out;

    unsigned char* xq = (unsigned char*)d_ws;                       // 4 MB
    unsigned char* wq = xq + (size_t)M_TOK * KB;                    // 8 MB
    float* swt = (float*)(wq + (size_t)N_OUT * KB);                 // 512 KB, [32][4096]
    float* sx  = swt + (size_t)(K_IN / 128) * N_OUT;                // 8 KB

    quant_fused_kernel<<<XBLK + WBLK, 256, 0, stream>>>(x, w, xq, sx, wq, swt);
    gemm_mx4_kernel<<<dim3(N_OUT / 256, M_TOK / 128), 512, 0, stream>>>(
        xq, sx, wq, swt, bias, out);
}

// Round 12
// 155.028 us; speedup vs baseline: 1.0428x; 1.0428x over previous
//
#include <hip/hip_runtime.h>

// y = q_tok(x) @ q_grp(W)^T + bias, factored exactly:
//   q(x) = g_x * s_x[m], q(W) = g_w * s_w[n,grp] (grp=128 along K)
//   y[m,n] = s_x[m] * sum_grp s_w[n,grp] * (sum_{k in grp} g_x g_w)
// R17 = R15 verbatim (session best, 155.2 us). Final lock-in.
// Gemm: R12 structure -- tile 128x128, wave 64x64, BK=256 (two K-groups
// per period), double-buffered LDS w/ static t&1 slots, counted vmcnt(8),
// two lgkm-counted MFMA phases, 0-conflict 8-row-period swizzle, setprio.
// Falsified levers this session: occupancy (R9), XCD remap (R10), sync
// rate (R12-neutral), B-direct (R13), no-LDS (R14), w-coalesce (R15-
// neutral), 8-phase deep pipeline (R7/R16 both regressed).
// Quant: coalesced float4 both roles, nibble-packed stores.

#define M_TOK 2048
#define N_OUT 4096
#define K_IN  4096
#define KB    2048    // packed fp4 bytes per K row (K_IN/2)
#define XBLK  2048    // x-role: one block per token row
#define WBLK  8192    // w-role: 2048 floats (16 groups) per block

typedef __attribute__((ext_vector_type(4))) int   int4v;
typedef __attribute__((ext_vector_type(8))) int   int8v;
typedef __attribute__((ext_vector_type(4))) float floatx4;

// fp4-e2m1 nibble via scale-premultiplied decision thresholds
// T = {.25,.75,1.25,1.75,2.5,3.5,5}*scale; codes 0..7 = {0,.5,1,1.5,2,3,4,6}
__device__ __forceinline__ unsigned int q_nib(
    float v, float t0, float t1, float t2, float t3, float t4, float t5, float t6)
{
    float a = fabsf(v);
    unsigned int m =
        a < t0 ? 0u : a < t1 ? 1u : a < t2 ? 2u : a < t3 ? 3u :
        a < t4 ? 4u : a < t5 ? 5u : a < t6 ? 6u : 7u;
    return m | ((__float_as_uint(v) >> 28) & 0x8u);
}

#define MK_THR(scale) \
    const float t0 = 0.25f * (scale), t1 = 0.75f * (scale), \
                t2 = 1.25f * (scale), t3 = 1.75f * (scale), \
                t4 = 2.5f  * (scale), t5 = 3.5f  * (scale), \
                t6 = 5.0f  * (scale);

// ---------- fused quant: blocks [0,XBLK) per-token x, rest per-group w ----------
__global__ __launch_bounds__(256) void quant_fused_kernel(
    const float* __restrict__ x, const float* __restrict__ w,
    unsigned char* __restrict__ xq, float* __restrict__ sx,
    unsigned char* __restrict__ wq, float* __restrict__ swt)
{
    const int t = threadIdx.x;
    const int lane = t & 63, wid = t >> 6;

    if (blockIdx.x < XBLK) {
        // ---- per-token row of 4096: clamp [-3,3], scale = absmax/6 ----
        // coalesced: phase i loads float4 at i*1024 + t*4 (16B/lane contiguous)
        const int row = blockIdx.x;
        const float* xr = x + (size_t)row * K_IN;
        float4 v[4];
        float amax = 0.0f;
        #pragma unroll
        for (int i = 0; i < 4; i++) {
            float4 a = *(const float4*)(xr + i * 1024 + t * 4);
            a.x = fminf(fmaxf(a.x, -3.0f), 3.0f);
            a.y = fminf(fmaxf(a.y, -3.0f), 3.0f);
            a.z = fminf(fmaxf(a.z, -3.0f), 3.0f);
            a.w = fminf(fmaxf(a.w, -3.0f), 3.0f);
            v[i] = a;
            amax = fmaxf(amax, fmaxf(fmaxf(fabsf(a.x), fabsf(a.y)),
                                     fmaxf(fabsf(a.z), fabsf(a.w))));
        }
        #pragma unroll
        for (int off = 32; off; off >>= 1)
            amax = fmaxf(amax, __shfl_xor(amax, off));
        __shared__ float smax[4];
        if (lane == 0) smax[wid] = amax;
        __syncthreads();
        amax = fmaxf(fmaxf(smax[0], smax[1]), fmaxf(smax[2], smax[3]));

        const float scale = amax / 6.0f;
        if (t == 0) sx[row] = scale;
        MK_THR(scale);
        unsigned char* xo = xq + (size_t)row * KB;
        #pragma unroll
        for (int i = 0; i < 4; i++) {
            unsigned int u = q_nib(v[i].x, t0,t1,t2,t3,t4,t5,t6)
                           | (q_nib(v[i].y, t0,t1,t2,t3,t4,t5,t6) << 4)
                           | (q_nib(v[i].z, t0,t1,t2,t3,t4,t5,t6) << 8)
                           | (q_nib(v[i].w, t0,t1,t2,t3,t4,t5,t6) << 12);
            *(unsigned short*)(xo + i * 512 + t * 2) = (unsigned short)u;
        }
    } else {
        // ---- per-group w: block = 2048 floats = 16 groups. COALESCED:
        // phase p, thread t owns floats [p*1024 + t*4, +4) (16B/lane
        // contiguous), all inside group p*8 + (t>>5). 32-lane cluster
        // reduce; output bytes/layout identical to previous rounds. ----
        const int b = blockIdx.x - XBLK;
        const float* base = w + (size_t)b * 2048;
        float4 va = *(const float4*)(base + t * 4);
        float4 vb = *(const float4*)(base + 1024 + t * 4);
        #pragma unroll
        for (int p = 0; p < 2; p++) {
            float4 a = p ? vb : va;
            float amax = fmaxf(fmaxf(fabsf(a.x), fabsf(a.y)),
                               fmaxf(fabsf(a.z), fabsf(a.w)));
            #pragma unroll
            for (int off = 16; off; off >>= 1)   // reduce 32-lane cluster
                amax = fmaxf(amax, __shfl_xor(amax, off));
            const float scale = amax / 6.0f;
            const int G = b * 16 + p * 8 + (t >> 5);  // flat group = n*32+gk
            if ((t & 31) == 0)
                swt[(size_t)(G & 31) * N_OUT + (G >> 5)] = scale;
            MK_THR(scale);
            unsigned int u = q_nib(a.x, t0,t1,t2,t3,t4,t5,t6)
                           | (q_nib(a.y, t0,t1,t2,t3,t4,t5,t6) << 4)
                           | (q_nib(a.z, t0,t1,t2,t3,t4,t5,t6) << 8)
                           | (q_nib(a.w, t0,t1,t2,t3,t4,t5,t6) << 12);
            *(unsigned short*)(wq + (size_t)b * 1024 + p * 512 + t * 2) =
                (unsigned short)u;
        }
    }
}

// ---------- async 16B global->LDS ----------
__device__ __forceinline__ void gld16(const unsigned char* g, unsigned char* l) {
    __builtin_amdgcn_global_load_lds(
        (const __attribute__((address_space(1))) void*)g,
        (__attribute__((address_space(3))) void*)l, 16, 0, 0);
}

// fragment read with the 8-row-period swizzle (verified 0-conflict, R9/R11)
__device__ __forceinline__ int4v frag4(const unsigned char* buf, int row, int lq) {
    const int slot = (lq + (row >> 1)) & 3;
    return *(const int4v*)&buf[row * 64 + slot * 16];
}
__device__ __forceinline__ int8v ext8(int4v d) {
    return (int8v){d[0], d[1], d[2], d[3], 0, 0, 0, 0};
}

// ---------- MX-fp4 GEMM, BK=256 = two quant groups per barrier period ----------
// (R12 verbatim -- best measured.) Tile 128x128, 4 waves (2m x 2n), wave
// tile 64x64. Per period: stage next super-tile (8 gld16), vmcnt(8), B1,
// reads g0 (12 ds) | reads g1 (12 ds), lgkm(12) -> 16 MFMA (g0), lgkm(0)
// -> B2 (release) -> 16 MFMA (g1). Static t&1 slot index.
__global__ __launch_bounds__(256, 2) void gemm_mx4_kernel(
    const unsigned char* __restrict__ A, const float* __restrict__ sx,
    const unsigned char* __restrict__ B, const float* __restrict__ swt,
    const float* __restrict__ bias, float* __restrict__ C)
{
    __shared__ __align__(16) unsigned char As[2][2][128 * 64]; // 32 KB
    __shared__ __align__(16) unsigned char Bs[2][2][128 * 64]; // 32 KB
    __shared__ __align__(16) float svs[32][128];               // 16 KB

    const int tid = threadIdx.x;
    const int m0 = blockIdx.y * 128;
    const int n0 = blockIdx.x * 128;
    const int lane = tid & 63;
    const int wid  = tid >> 6;
    const int wm = (wid & 1) * 64;   // wave m-offset: 0/64
    const int wn = (wid >> 1) * 64;  // wave n-offset: 0/64
    const int lr = lane & 15;
    const int lq = lane >> 4;

    floatx4 mast[4][4] = {};

    // staging addresses: swizzle phys-slot = (c + (row>>1)) & 3; inverse on
    // the global source so the LDS dest stays wave-uniform + lane*16.
    // Per sub-tile (128 rows x 64 B): 512 chunks -> 2/thread per operand.
    const unsigned char* gA[2];
    const unsigned char* gB[2];
    int ldst[2];
    #pragma unroll
    for (int i = 0; i < 2; i++) {
        const int P = tid + i * 256;
        const int row = P >> 2, ph = P & 3;
        const int c = (ph - (row >> 1)) & 3;     // logical chunk at phys ph
        gA[i] = A + (size_t)(m0 + row) * KB + c * 16;
        gB[i] = B + (size_t)(n0 + row) * KB + c * 16;
        ldst[i] = P * 16;
    }

    // STAGE one super-tile (K-groups 2t, 2t+1): 8 gld16
#define STAGE(tt, ss) do {                                     \
        const int koff_ = (tt) * 128;                          \
        _Pragma("unroll")                                      \
        for (int j_ = 0; j_ < 2; j_++) {                       \
            gld16(gA[0] + koff_ + j_ * 64, &As[ss][j_][ldst[0]]); \
            gld16(gA[1] + koff_ + j_ * 64, &As[ss][j_][ldst[1]]); \
            gld16(gB[0] + koff_ + j_ * 64, &Bs[ss][j_][ldst[0]]); \
            gld16(gB[1] + koff_ + j_ * 64, &Bs[ss][j_][ldst[1]]); \
        }                                                      \
    } while (0)

    // one-time stage of this block's weight scales: swt[g][n0..n0+128)
    // (loads issued before STAGE so their waits don't drain gld16s)
    {
        float4 tmp[4];
        #pragma unroll
        for (int i = 0; i < 4; i++) {
            const int flat = tid + i * 256;      // float4 index, 1024 total
            const int g = flat >> 5, c = (flat & 31) << 2;
            tmp[i] = *(const float4*)(swt + (size_t)g * N_OUT + n0 + c);
        }
        #pragma unroll
        for (int i = 0; i < 4; i++) {
            const int flat = tid + i * 256;
            const int g = flat >> 5, c = (flat & 31) << 2;
            *(float4*)&svs[g][c] = tmp[i];
        }
    }
    // prologue: stage super-tile 0 into slot 0
    STAGE(0, 0);
    asm volatile("s_waitcnt lgkmcnt(0)" ::: "memory");  // svs ds_writes done

    const floatx4 zero = {0.0f, 0.0f, 0.0f, 0.0f};

    #pragma unroll 2
    for (int t = 0; t < 16; t++) {
        const int cur = t & 1;
        if (t < 15) {
            STAGE(t + 1, cur ^ 1);               // 8 loads in flight
            asm volatile("s_waitcnt vmcnt(8)" ::: "memory");  // tile t ready
        } else {
            asm volatile("s_waitcnt vmcnt(0)" ::: "memory");
        }
        __builtin_amdgcn_s_barrier();            // B1: slot[cur] published
        __builtin_amdgcn_sched_barrier(0);

        // ---- group 0 reads: sv (4 b32) + 8 b128 = 12 ds ops ----
        float sv0[4];
        #pragma unroll
        for (int ni = 0; ni < 4; ni++)
            sv0[ni] = svs[2 * t][wn + ni * 16 + lr];
        int4v a0[4], b0[4];
        #pragma unroll
        for (int mi = 0; mi < 4; mi++)
            a0[mi] = frag4(As[cur][0], wm + mi * 16 + lr, lq);
        #pragma unroll
        for (int ni = 0; ni < 4; ni++)
            b0[ni] = frag4(Bs[cur][0], wn + ni * 16 + lr, lq);
        __builtin_amdgcn_sched_barrier(0);       // pin g0/g1 issue split

        // ---- group 1 reads: 12 ds ops ----
        float sv1[4];
        #pragma unroll
        for (int ni = 0; ni < 4; ni++)
            sv1[ni] = svs[2 * t + 1][wn + ni * 16 + lr];
        int4v a1[4], b1[4];
        #pragma unroll
        for (int mi = 0; mi < 4; mi++)
            a1[mi] = frag4(As[cur][1], wm + mi * 16 + lr, lq);
        #pragma unroll
        for (int ni = 0; ni < 4; ni++)
            b1[ni] = frag4(Bs[cur][1], wn + ni * 16 + lr, lq);

        // ---- phase A: g0 MFMAs while g1's 12 ds ops are in flight ----
        asm volatile("s_waitcnt lgkmcnt(12)" ::: "memory");
        __builtin_amdgcn_sched_barrier(0);       // rule #18
        __builtin_amdgcn_s_setprio(1);
        #pragma unroll
        for (int mi = 0; mi < 4; mi++)
            #pragma unroll
            for (int ni = 0; ni < 4; ni++) {
                floatx4 tacc = __builtin_amdgcn_mfma_scale_f32_16x16x128_f8f6f4(
                    ext8(a0[mi]), ext8(b0[ni]), zero, 4, 4,   // fp4
                    0, 0x7F7F7F7F, 0, 0x7F7F7F7F);
                mast[mi][ni] += sv0[ni] * tacc;
            }
        __builtin_amdgcn_s_setprio(0);

        // ---- release + phase B: g1 MFMAs overlap next staging ----
        asm volatile("s_waitcnt lgkmcnt(0)" ::: "memory");
        __builtin_amdgcn_sched_barrier(0);       // rule #18
        __builtin_amdgcn_s_barrier();            // B2: slot[cur] free
        __builtin_amdgcn_s_setprio(1);
        #pragma unroll
        for (int mi = 0; mi < 4; mi++)
            #pragma unroll
            for (int ni = 0; ni < 4; ni++) {
                floatx4 tacc = __builtin_amdgcn_mfma_scale_f32_16x16x128_f8f6f4(
                    ext8(a1[mi]), ext8(b1[ni]), zero, 4, 4,
                    0, 0x7F7F7F7F, 0, 0x7F7F7F7F);
                mast[mi][ni] += sv1[ni] * tacc;
            }
        __builtin_amdgcn_s_setprio(0);
    }
#undef STAGE

    // epilogue: C/D layout col=lane&15, row=(lane>>4)*4+reg [m89/m91]
    #pragma unroll
    for (int mi = 0; mi < 4; mi++) {
        const int rbase = m0 + wm + mi * 16 + lq * 4;
        #pragma unroll
        for (int ni = 0; ni < 4; ni++) {
            const int cc = n0 + wn + ni * 16 + lr;
            const float bb = bias[cc];
            #pragma unroll
            for (int r = 0; r < 4; r++)
                C[(size_t)(rbase + r) * N_OUT + cc] =
                    sx[rbase + r] * mast[mi][ni][r] + bb;
        }
    }
}

extern "C" void kernel_launch(void* const* d_in, const int* in_sizes, int n_in,
                              void* d_out, int out_size, void* d_ws, size_t ws_size,
                              hipStream_t stream) {
    const float* x    = (const float*)d_in[0];
    const float* w    = (const float*)d_in[1];
    const float* bias = (const float*)d_in[2];
    float* out = (float*)d_out;

    unsigned char* xq = (unsigned char*)d_ws;                       // 4 MB
    unsigned char* wq = xq + (size_t)M_TOK * KB;                    // 8 MB
    float* swt = (float*)(wq + (size_t)N_OUT * KB);                 // 512 KB, [32][4096]
    float* sx  = swt + (size_t)(K_IN / 128) * N_OUT;                // 8 KB

    quant_fused_kernel<<<XBLK + WBLK, 256, 0, stream>>>(x, w, xq, sx, wq, swt);
    gemm_mx4_kernel<<<dim3(N_OUT / 128, M_TOK / 128), 256, 0, stream>>>(
        xq, sx, wq, swt, bias, out);
}